// Round 1
// baseline (348.085 us; speedup 1.0000x reference)
//
#include <hip/hip_runtime.h>
#include <hip/hip_bf16.h>
#include <math.h>

// Problem constants (match reference)
#define BB  32
#define SS  4096
#define VV  256
#define DD  256
#define CC  2
#define WIN 64
#define NW  64   // SS/WIN

typedef unsigned short ushort_t;
typedef unsigned int   uint_t;
typedef __attribute__((ext_vector_type(8))) short short8;    // 8 bf16 (4 VGPRs)
typedef __attribute__((ext_vector_type(4))) float f32x4;

// Workspace layout (byte offsets). Total 573440 B.
#define WS_ATHI_B 0u          // ushort Athi[64][64]   8192  (A-op layout: [t][s])
#define WS_ATLO_B 8192u       // ushort Atlo[64][64]   8192
#define WS_GPK_B  16384u      // uint   gpk[256][256]  262144 (hi<<16 | lo per elem)
#define WS_W2HI_B 278528u     // ushort W2hi[256][256] 131072
#define WS_W2LO_B 409600u     // ushort W2lo[256][256] 131072
#define WS_POOL_B 540672u     // float  pool[32][256]  32768

#define HP 264    // H2 plane row stride in shorts (256 + 8 pad)

__device__ __forceinline__ float fast_tanh(float v) {
  float e = __expf(2.0f * v);
  return 1.0f - __fdividef(2.0f, e + 1.0f);
}

// Truncation-based bf16 split: v ~= hi + lo with |err| <= 2^-17 * |v|.
__device__ __forceinline__ uint_t split_pack(float v) {
  uint_t b  = __float_as_uint(v);
  uint_t hi = b & 0xffff0000u;
  float  r  = v - __uint_as_float(hi);
  uint_t lo = __float_as_uint(r) >> 16;
  return hi | lo;
}

// Pack hi/lo halves of two packed u32 into bf16 pair dwords via v_perm.
__device__ __forceinline__ uint_t perm_hi(uint_t p0, uint_t p1) {
  return __builtin_amdgcn_perm(p1, p0, 0x07060302u);
}
__device__ __forceinline__ uint_t perm_lo(uint_t p0, uint_t p1) {
  return __builtin_amdgcn_perm(p1, p0, 0x05040100u);
}

union u4s8 { uint_t u[4]; short8 v; };

// ---------------------------------------------------------------------------
// Prep grid (1090 blocks): unchanged from previous verified version.
// ---------------------------------------------------------------------------
__global__ __launch_bounds__(256) void prep_kernel(
    const float* __restrict__ emb, const float* __restrict__ W1,
    const float* __restrict__ W2, char* __restrict__ ws)
{
  const int blk = blockIdx.x;
  const int tid = threadIdx.x;
  ushort_t* Athi = (ushort_t*)(ws + WS_ATHI_B);
  ushort_t* Atlo = (ushort_t*)(ws + WS_ATLO_B);
  uint_t*   gpk  = (uint_t*)  (ws + WS_GPK_B);
  ushort_t* W2hi = (ushort_t*)(ws + WS_W2HI_B);
  ushort_t* W2lo = (ushort_t*)(ws + WS_W2LO_B);
  float*    pool = (float*)   (ws + WS_POOL_B);

  if (blk == 0) {
    if (tid < WIN) {
      const int s = tid;
      const float omega = 60.0f * 2.0f * 3.14159265358979323846f / 4095.0f;
      float row[WIN];
      float sum = 0.0f;
      for (int t = 0; t < WIN; ++t) {
        float e = expf(cosf(omega * (float)(s - t)));
        row[t] = e;
        sum += e;
      }
      const float inv = 1.0f / sum;
      for (int t = 0; t < WIN; ++t) {
        uint_t pk = split_pack(row[t] * inv);
        Athi[t * WIN + s] = (ushort_t)(pk >> 16);
        Atlo[t * WIN + s] = (ushort_t)(pk & 0xffffu);
      }
    }
  } else if (blk == 1) {
    for (int i = tid; i < BB * DD; i += 256) pool[i] = 0.0f;
  } else if (blk < 1026) {
    const int gv = blk - 2;            // 0..1023
    const int d0 = (gv & 15) * 16;     // 16 d-columns
    const int v0 = (gv >> 4) * 4;      // 4 v-rows
    __shared__ float er[4 * DD];       // 4 KB
    __shared__ float ps[4][16][17];    // padded partials
    *(float4*)(er + tid * 4) = *(const float4*)(emb + v0 * DD + tid * 4);
    __syncthreads();
    const int kq = tid & 15;           // k-strip: [16kq, 16kq+16)
    const int dl = tid >> 4;           // 0..15
    const int d  = d0 + dl;
    float4 wv[4];
    #pragma unroll
    for (int j = 0; j < 4; ++j)
      wv[j] = *(const float4*)(W1 + d * DD + 16 * kq + 4 * j);  // coalesced
    #pragma unroll
    for (int v = 0; v < 4; ++v) {
      float a = 0.0f;
      #pragma unroll
      for (int j = 0; j < 4; ++j) {
        float4 e = *(const float4*)(er + v * DD + 16 * kq + 4 * j);
        a += e.x * wv[j].x + e.y * wv[j].y + e.z * wv[j].z + e.w * wv[j].w;
      }
      ps[v][dl][kq] = a;
    }
    __syncthreads();
    if (tid < 64) {
      const int v = tid >> 4, dr = tid & 15;
      float s = 0.0f;
      #pragma unroll
      for (int k = 0; k < 16; ++k) s += ps[v][dr][k];
      gpk[(v0 + v) * DD + d0 + dr] = split_pack(s);
    }
  } else {
    const int c0 = (blk - 1026) * 4;
    #pragma unroll
    for (int i = 0; i < 4; ++i) {
      const int c = c0 + i;
      uint_t pk = split_pack(W2[c * DD + tid]);
      W2hi[c * DD + tid] = (ushort_t)(pk >> 16);
      W2lo[c * DD + tid] = (ushort_t)(pk & 0xffffu);
    }
  }
}

// ---------------------------------------------------------------------------
// Main fused kernel — PERSISTENT PIPELINE version.
// 512 blocks (2/CU exactly), each handles 4 consecutive windows of one batch.
// Per window:
//   R1: attention MFMAs, with (a) prev window's pooling-tanh (P5) interleaved
//       per-mt and (b) tanh+split+LDS-store (P3) fused per-mt -> independent
//       VALU chains sit adjacent to MFMA issue, so the wave dual-feeds both
//       pipes instead of phase-locking.
//   R2: W2 MFMAs; next window's gpk gather (32 L2 loads) issued at k0==4 so
//       its latency hides under ~1800 cycles of MFMA.
// acc2 is single-buffered: consumed (P5) at top of next R1, re-zeroed in R2.
// Pool partials live in 2 regs across all 4 windows -> 1 atomic/wave (was 4).
// LDS write swizzle: column ds = d ^ (((t>>2)&3)<<3). Fixes the 4-way b16
// write conflict (row stride 132 dw == 4 mod 32 put quads {0,2},{1,3} on the
// same banks); the matching read offset dsl ^ (u<<3) keeps ds_read_b128 at
// the exact 8-phase minimum (verified: uniform 8 dwords/bank), 16B-aligned.
// ---------------------------------------------------------------------------
__global__ __launch_bounds__(512, 4) void main_kernel(
    const int*      __restrict__ x,    const uint_t* __restrict__ gpk,
    const ushort_t* __restrict__ Athi, const ushort_t* __restrict__ Atlo,
    const float*    __restrict__ b1,
    const ushort_t* __restrict__ W2hi, const ushort_t* __restrict__ W2lo,
    const float*    __restrict__ b2,   float* __restrict__ pool)
{
  __shared__ ushort_t Hhi[WIN][HP];   // 33792 B
  __shared__ ushort_t Hlo[WIN][HP];   // 33792 B (total 67584 -> 2 blocks/CU)

  const int tid  = threadIdx.x;
  const int lane = tid & 63;
  const int w    = tid >> 6;       // 0..7
  const int quad = lane >> 4;
  const int l16  = lane & 15;
  const int b  = blockIdx.x >> 4;         // batch
  const int n0 = (blockIdx.x & 15) << 2;  // first of 4 windows

  const int dbase = 32 * w;        // this wave's d-slice (R1) == c-slice (R2)
  const int cbase = dbase;
  const int u     = l16 >> 2;      // read-swizzle selector ((t>>2)&3 for t=mt*16+l16)

  float b1v[2], b2v[2];
  #pragma unroll
  for (int nt = 0; nt < 2; ++nt) {
    b1v[nt] = b1[dbase + 16 * nt + l16];
    b2v[nt] = b2[cbase + 16 * nt + l16];
  }

  float pres0 = 0.0f, pres1 = 0.0f;   // pooled partials across all 4 windows
  f32x4 acc2[4][2];                   // carries window i's results into R1(i+1)
  uint_t q[2][2][8];                  // gather regs (refilled mid-R2)

  // ---- prologue: gather for window n0 ----
  {
    const int xv = x[b * SS + n0 * WIN + lane];
    #pragma unroll
    for (int k0 = 0; k0 < 2; ++k0) {
      const int sl = k0 * 32 + quad * 8;
      int xs[8];
      #pragma unroll
      for (int j = 0; j < 8; ++j) xs[j] = __shfl(xv, sl + j, 64);
      #pragma unroll
      for (int nt = 0; nt < 2; ++nt) {
        const int d = dbase + 16 * nt + l16;
        #pragma unroll
        for (int j = 0; j < 8; ++j) q[k0][nt][j] = gpk[xs[j] * DD + d];
      }
    }
  }

  #pragma unroll 1
  for (int i = 0; i < 4; ++i) {
    // ===== R1: attention MFMA + fused P3 + deferred P5(prev) =====
    short8 bh[2][2], bl[2][2];
    #pragma unroll
    for (int k0 = 0; k0 < 2; ++k0)
      #pragma unroll
      for (int nt = 0; nt < 2; ++nt) {
        u4s8 h, l;
        #pragma unroll
        for (int p = 0; p < 4; ++p) {
          h.u[p] = perm_hi(q[k0][nt][2 * p], q[k0][nt][2 * p + 1]);
          l.u[p] = perm_lo(q[k0][nt][2 * p], q[k0][nt][2 * p + 1]);
        }
        bh[k0][nt] = h.v;
        bl[k0][nt] = l.v;
      }

    #pragma unroll
    for (int mt = 0; mt < 4; ++mt) {
      // deferred pooling-tanh of PREV window (indep. VALU under this mt's MFMAs)
      if (i > 0) {
        float s0 = 0.0f, s1 = 0.0f;
        #pragma unroll
        for (int r = 0; r < 4; ++r) {
          s0 += fast_tanh(acc2[mt][0][r] + b2v[0]);
          s1 += fast_tanh(acc2[mt][1][r] + b2v[1]);
        }
        pres0 += s0;
        pres1 += s1;
      }
      f32x4 a1[2];
      a1[0] = (f32x4)0.0f;
      a1[1] = (f32x4)0.0f;
      #pragma unroll
      for (int k0 = 0; k0 < 2; ++k0) {
        const int sl = k0 * 32 + quad * 8;
        const int t  = mt * 16 + l16;
        short8 ah = *(const short8*)(Athi + t * WIN + sl);   // L1-resident
        short8 al = *(const short8*)(Atlo + t * WIN + sl);
        #pragma unroll
        for (int nt = 0; nt < 2; ++nt) {
          a1[nt] = __builtin_amdgcn_mfma_f32_16x16x32_bf16(ah, bh[k0][nt], a1[nt], 0, 0, 0);
          a1[nt] = __builtin_amdgcn_mfma_f32_16x16x32_bf16(ah, bl[k0][nt], a1[nt], 0, 0, 0);
          a1[nt] = __builtin_amdgcn_mfma_f32_16x16x32_bf16(al, bh[k0][nt], a1[nt], 0, 0, 0);
        }
      }
      // P3 for this mt: tanh(+b1), split, swizzled store
      #pragma unroll
      for (int nt = 0; nt < 2; ++nt) {
        const int d  = dbase + 16 * nt + l16;
        const int ds = d ^ (quad << 3);     // (t>>2)&3 == quad for t=mt*16+quad*4+r
        #pragma unroll
        for (int r = 0; r < 4; ++r) {
          const int t = mt * 16 + quad * 4 + r;
          float hv = fast_tanh(a1[nt][r] + b1v[nt]);
          uint_t pk = split_pack(hv);
          Hhi[t][ds] = (ushort_t)(pk >> 16);
          Hlo[t][ds] = (ushort_t)(pk & 0xffffu);
        }
      }
    }
    __syncthreads();   // H(i) complete

    // ===== R2: W2 matmul =====
    #pragma unroll
    for (int mt = 0; mt < 4; ++mt) {
      acc2[mt][0] = (f32x4)0.0f;
      acc2[mt][1] = (f32x4)0.0f;
    }

    #pragma unroll
    for (int k0 = 0; k0 < 8; ++k0) {
      // mid-loop: prefetch next window's gather under the remaining MFMAs
      if (k0 == 4 && i < 3) {
        const int xv = x[b * SS + (n0 + i + 1) * WIN + lane];
        #pragma unroll
        for (int kk = 0; kk < 2; ++kk) {
          const int sl = kk * 32 + quad * 8;
          int xs[8];
          #pragma unroll
          for (int j = 0; j < 8; ++j) xs[j] = __shfl(xv, sl + j, 64);
          #pragma unroll
          for (int nt = 0; nt < 2; ++nt) {
            const int d = dbase + 16 * nt + l16;
            #pragma unroll
            for (int j = 0; j < 8; ++j) q[kk][nt][j] = gpk[xs[j] * DD + d];
          }
        }
      }
      const int dsl = k0 * 32 + quad * 8;
      short8 w2h[2], w2l[2];
      #pragma unroll
      for (int nt = 0; nt < 2; ++nt) {
        const int c = cbase + 16 * nt + l16;
        w2h[nt] = *(const short8*)(W2hi + c * DD + dsl);   // L2-resident
        w2l[nt] = *(const short8*)(W2lo + c * DD + dsl);
      }
      const int dsw = dsl ^ (u << 3);       // undo write swizzle for row t=mt*16+l16
      #pragma unroll
      for (int mt = 0; mt < 4; ++mt) {
        const int t = mt * 16 + l16;
        short8 ah = *(const short8*)(&Hhi[t][dsw]);   // ds_read_b128, 8-phase min
        short8 al = *(const short8*)(&Hlo[t][dsw]);
        #pragma unroll
        for (int nt = 0; nt < 2; ++nt) {
          acc2[mt][nt] = __builtin_amdgcn_mfma_f32_16x16x32_bf16(ah, w2h[nt], acc2[mt][nt], 0, 0, 0);
          acc2[mt][nt] = __builtin_amdgcn_mfma_f32_16x16x32_bf16(ah, w2l[nt], acc2[mt][nt], 0, 0, 0);
          acc2[mt][nt] = __builtin_amdgcn_mfma_f32_16x16x32_bf16(al, w2h[nt], acc2[mt][nt], 0, 0, 0);
        }
      }
    }
    __syncthreads();   // all waves done reading H(i) before R1(i+1) overwrites
  }

  // ---- epilogue: P5 of last window + single reduce/atomic per wave ----
  #pragma unroll
  for (int mt = 0; mt < 4; ++mt) {
    #pragma unroll
    for (int r = 0; r < 4; ++r) {
      pres0 += fast_tanh(acc2[mt][0][r] + b2v[0]);
      pres1 += fast_tanh(acc2[mt][1][r] + b2v[1]);
    }
  }
  {
    float p = pres0;
    p += __shfl_xor(p, 16, 64);
    p += __shfl_xor(p, 32, 64);
    if (quad == 0) atomicAdd(&pool[b * DD + cbase + l16], p);
    float p1 = pres1;
    p1 += __shfl_xor(p1, 16, 64);
    p1 += __shfl_xor(p1, 32, 64);
    if (quad == 0) atomicAdd(&pool[b * DD + cbase + 16 + l16], p1);
  }
}

// ---------------------------------------------------------------------------
// Final: out[b,c] = (pool[b,:] / S) . Wc[c,:] + bc[c].  One block per b.
// ---------------------------------------------------------------------------
__global__ __launch_bounds__(64) void final_kernel(
    const float* __restrict__ pool, const float* __restrict__ Wc,
    const float* __restrict__ bc, float* __restrict__ out)
{
  const int b = blockIdx.x;
  const int t = threadIdx.x;
  float p0 = 0.0f, p1 = 0.0f;
  #pragma unroll
  for (int j = 0; j < 4; ++j) {
    float pv = pool[b * DD + t + 64 * j];
    p0 += pv * Wc[t + 64 * j];
    p1 += pv * Wc[DD + t + 64 * j];
  }
  #pragma unroll
  for (int off = 32; off; off >>= 1) {
    p0 += __shfl_xor(p0, off, 64);
    p1 += __shfl_xor(p1, off, 64);
  }
  if (t == 0) {
    out[b * CC + 0] = p0 * (1.0f / SS) + bc[0];
    out[b * CC + 1] = p1 * (1.0f / SS) + bc[1];
  }
}

extern "C" void kernel_launch(void* const* d_in, const int* in_sizes, int n_in,
                              void* d_out, int out_size, void* d_ws, size_t ws_size,
                              hipStream_t stream) {
  const int*   x   = (const int*)  d_in[0];
  const float* emb = (const float*)d_in[1];
  const float* W1  = (const float*)d_in[2];
  const float* b1  = (const float*)d_in[3];
  const float* W2  = (const float*)d_in[4];
  const float* b2  = (const float*)d_in[5];
  const float* Wc  = (const float*)d_in[6];
  const float* bc  = (const float*)d_in[7];
  float* out = (float*)d_out;
  char*  ws  = (char*)d_ws;

  prep_kernel<<<1090, 256, 0, stream>>>(emb, W1, W2, ws);
  main_kernel<<<BB * NW / 4, 512, 0, stream>>>(
      x,
      (const uint_t*)  (ws + WS_GPK_B),
      (const ushort_t*)(ws + WS_ATHI_B), (const ushort_t*)(ws + WS_ATLO_B),
      b1,
      (const ushort_t*)(ws + WS_W2HI_B), (const ushort_t*)(ws + WS_W2LO_B),
      b2,
      (float*)(ws + WS_POOL_B));
  final_kernel<<<BB, 64, 0, stream>>>((const float*)(ws + WS_POOL_B), Wc, bc, out);
}

// Round 2
// 278.120 us; speedup vs baseline: 1.2516x; 1.2516x over previous
//
#include <hip/hip_runtime.h>
#include <hip/hip_bf16.h>
#include <math.h>

// Problem constants (match reference)
#define BB  32
#define SS  4096
#define VV  256
#define DD  256
#define CC  2
#define WIN 64
#define NW  64   // SS/WIN

typedef unsigned short ushort_t;
typedef unsigned int   uint_t;
typedef __attribute__((ext_vector_type(8))) short short8;    // 8 bf16 (4 VGPRs)
typedef __attribute__((ext_vector_type(4))) float f32x4;

// Workspace layout (byte offsets). Total 573440 B.
#define WS_ATHI_B 0u          // ushort Athi[64][64]   8192  (A-op layout: [t][s])
#define WS_ATLO_B 8192u       // ushort Atlo[64][64]   8192
#define WS_GPK_B  16384u      // uint   gpk[256][256]  262144 (hi<<16 | lo per elem)
#define WS_W2HI_B 278528u     // ushort W2hi[256][256] 131072
#define WS_W2LO_B 409600u     // ushort W2lo[256][256] 131072
#define WS_POOL_B 540672u     // float  pool[32][256]  32768

#define HP 264    // H plane row stride in shorts (256 + 8 pad; 132 dw = 4 mod 32)

__device__ __forceinline__ float fast_tanh(float v) {
  float e = __expf(2.0f * v);
  return 1.0f - __fdividef(2.0f, e + 1.0f);
}

// Truncation-based bf16 split: v ~= hi + lo with |err| <= 2^-17 * |v|.
__device__ __forceinline__ uint_t split_pack(float v) {
  uint_t b  = __float_as_uint(v);
  uint_t hi = b & 0xffff0000u;
  float  r  = v - __uint_as_float(hi);
  uint_t lo = __float_as_uint(r) >> 16;
  return hi | lo;
}

// Pack hi/lo halves of two packed u32 into bf16 pair dwords via v_perm.
__device__ __forceinline__ uint_t perm_hi(uint_t p0, uint_t p1) {
  return __builtin_amdgcn_perm(p1, p0, 0x07060302u);
}
__device__ __forceinline__ uint_t perm_lo(uint_t p0, uint_t p1) {
  return __builtin_amdgcn_perm(p1, p0, 0x05040100u);
}

union u4s8 { uint_t u[4]; short8 v; };

// ---------------------------------------------------------------------------
// Prep grid (1090 blocks): unchanged from the verified 123 us version.
// ---------------------------------------------------------------------------
__global__ __launch_bounds__(256) void prep_kernel(
    const float* __restrict__ emb, const float* __restrict__ W1,
    const float* __restrict__ W2, char* __restrict__ ws)
{
  const int blk = blockIdx.x;
  const int tid = threadIdx.x;
  ushort_t* Athi = (ushort_t*)(ws + WS_ATHI_B);
  ushort_t* Atlo = (ushort_t*)(ws + WS_ATLO_B);
  uint_t*   gpk  = (uint_t*)  (ws + WS_GPK_B);
  ushort_t* W2hi = (ushort_t*)(ws + WS_W2HI_B);
  ushort_t* W2lo = (ushort_t*)(ws + WS_W2LO_B);
  float*    pool = (float*)   (ws + WS_POOL_B);

  if (blk == 0) {
    if (tid < WIN) {
      const int s = tid;
      const float omega = 60.0f * 2.0f * 3.14159265358979323846f / 4095.0f;
      float row[WIN];
      float sum = 0.0f;
      for (int t = 0; t < WIN; ++t) {
        float e = expf(cosf(omega * (float)(s - t)));
        row[t] = e;
        sum += e;
      }
      const float inv = 1.0f / sum;
      for (int t = 0; t < WIN; ++t) {
        uint_t pk = split_pack(row[t] * inv);
        Athi[t * WIN + s] = (ushort_t)(pk >> 16);
        Atlo[t * WIN + s] = (ushort_t)(pk & 0xffffu);
      }
    }
  } else if (blk == 1) {
    for (int i = tid; i < BB * DD; i += 256) pool[i] = 0.0f;
  } else if (blk < 1026) {
    const int gv = blk - 2;            // 0..1023
    const int d0 = (gv & 15) * 16;     // 16 d-columns
    const int v0 = (gv >> 4) * 4;      // 4 v-rows
    __shared__ float er[4 * DD];       // 4 KB
    __shared__ float ps[4][16][17];    // padded partials
    *(float4*)(er + tid * 4) = *(const float4*)(emb + v0 * DD + tid * 4);
    __syncthreads();
    const int kq = tid & 15;           // k-strip: [16kq, 16kq+16)
    const int dl = tid >> 4;           // 0..15
    const int d  = d0 + dl;
    float4 wv[4];
    #pragma unroll
    for (int j = 0; j < 4; ++j)
      wv[j] = *(const float4*)(W1 + d * DD + 16 * kq + 4 * j);  // coalesced
    #pragma unroll
    for (int v = 0; v < 4; ++v) {
      float a = 0.0f;
      #pragma unroll
      for (int j = 0; j < 4; ++j) {
        float4 e = *(const float4*)(er + v * DD + 16 * kq + 4 * j);
        a += e.x * wv[j].x + e.y * wv[j].y + e.z * wv[j].z + e.w * wv[j].w;
      }
      ps[v][dl][kq] = a;
    }
    __syncthreads();
    if (tid < 64) {
      const int v = tid >> 4, dr = tid & 15;
      float s = 0.0f;
      #pragma unroll
      for (int k = 0; k < 16; ++k) s += ps[v][dr][k];
      gpk[(v0 + v) * DD + d0 + dr] = split_pack(s);
    }
  } else {
    const int c0 = (blk - 1026) * 4;
    #pragma unroll
    for (int i = 0; i < 4; ++i) {
      const int c = c0 + i;
      uint_t pk = split_pack(W2[c * DD + tid]);
      W2hi[c * DD + tid] = (ushort_t)(pk >> 16);
      W2lo[c * DD + tid] = (ushort_t)(pk & 0xffffu);
    }
  }
}

// ---------------------------------------------------------------------------
// Main fused kernel — HIGH-OCCUPANCY version.
// One block per (b, n) as in the verified 123 us kernel, but the window is
// processed in two 32-token halves through the SAME [32][HP] H buffers:
//   LDS 67.6 KB -> 33.8 KB  =>  4 blocks/CU (32 waves, 8/SIMD — the HW cap),
// doubling latency-hiding TLP. Counter evidence for this move: MfmaUtil 22%
// + VALUBusy 40% with LDS ~27% and L2 ~30% busy — nothing saturated, 38%
// dead time => latency-bound at 4 waves/SIMD.
// Register discipline (the round-1 spill lesson): no state is carried across
// phases beyond acc2[2][2] (16 VGPR). Gather is redone per half (L1/L2-hot),
// converted per-k0 (bh/bl 16 VGPR transient). Peak live ~56 VGPR < the 64
// cap at __launch_bounds__(512,8). All per-accumulator MFMA orders and the
// pooling addition sequence are bit-identical to the verified kernel.
// ---------------------------------------------------------------------------
__global__ __launch_bounds__(512, 8) void main_kernel(
    const int*      __restrict__ x,    const uint_t* __restrict__ gpk,
    const ushort_t* __restrict__ Athi, const ushort_t* __restrict__ Atlo,
    const float*    __restrict__ b1,
    const ushort_t* __restrict__ W2hi, const ushort_t* __restrict__ W2lo,
    const float*    __restrict__ b2,   float* __restrict__ pool)
{
  __shared__ ushort_t Hhi[32][HP];   // 16896 B
  __shared__ ushort_t Hlo[32][HP];   // 16896 B (total 33792 -> 4 blocks/CU)

  const int tid  = threadIdx.x;
  const int lane = tid & 63;
  const int w    = tid >> 6;       // 0..7
  const int quad = lane >> 4;
  const int l16  = lane & 15;
  const int b = blockIdx.x >> 6;
  const int n = blockIdx.x & 63;

  const int dbase = 32 * w;        // this wave's d-slice (P2) == c-slice (P4)
  const int cbase = dbase;

  const int xv = x[b * SS + n * WIN + lane];   // window token ids (1 VGPR)

  float b1v[2], b2v[2];
  #pragma unroll
  for (int nt = 0; nt < 2; ++nt) {
    b1v[nt] = b1[dbase + 16 * nt + l16];
    b2v[nt] = b2[cbase + 16 * nt + l16];
  }

  float pres0 = 0.0f, pres1 = 0.0f;   // pooled partials across both halves

  #pragma unroll
  for (int h = 0; h < 2; ++h) {
    const int tb = h * 32;           // token-half base row

    // ===== P2: attention MFMA for rows [tb, tb+32) =====
    f32x4 a1[2][2];
    #pragma unroll
    for (int mt = 0; mt < 2; ++mt)
      #pragma unroll
      for (int nt = 0; nt < 2; ++nt) a1[mt][nt] = (f32x4)0.0f;

    #pragma unroll
    for (int k0 = 0; k0 < 2; ++k0) {
      // gather + convert this k0's 32-token slice (16+16 VGPR transient)
      const int sl = k0 * 32 + quad * 8;
      short8 bh[2], bl[2];
      {
        uint_t qq[2][8];
        int xs[8];
        #pragma unroll
        for (int j = 0; j < 8; ++j) xs[j] = __shfl(xv, sl + j, 64);
        #pragma unroll
        for (int nt = 0; nt < 2; ++nt) {
          const int d = dbase + 16 * nt + l16;
          #pragma unroll
          for (int j = 0; j < 8; ++j) qq[nt][j] = gpk[xs[j] * DD + d];
        }
        #pragma unroll
        for (int nt = 0; nt < 2; ++nt) {
          u4s8 hh, ll;
          #pragma unroll
          for (int p = 0; p < 4; ++p) {
            hh.u[p] = perm_hi(qq[nt][2 * p], qq[nt][2 * p + 1]);
            ll.u[p] = perm_lo(qq[nt][2 * p], qq[nt][2 * p + 1]);
          }
          bh[nt] = hh.v;
          bl[nt] = ll.v;
        }
      }
      #pragma unroll
      for (int mt = 0; mt < 2; ++mt) {
        const int t = tb + mt * 16 + l16;
        short8 ah = *(const short8*)(Athi + t * WIN + sl);   // L1-resident
        short8 al = *(const short8*)(Atlo + t * WIN + sl);
        #pragma unroll
        for (int nt = 0; nt < 2; ++nt) {
          a1[mt][nt] = __builtin_amdgcn_mfma_f32_16x16x32_bf16(ah, bh[nt], a1[mt][nt], 0, 0, 0);
          a1[mt][nt] = __builtin_amdgcn_mfma_f32_16x16x32_bf16(ah, bl[nt], a1[mt][nt], 0, 0, 0);
          a1[mt][nt] = __builtin_amdgcn_mfma_f32_16x16x32_bf16(al, bh[nt], a1[mt][nt], 0, 0, 0);
        }
      }
    }

    // ===== P3: tanh(+b1), split, store to hi/lo planes (local rows) =====
    #pragma unroll
    for (int nt = 0; nt < 2; ++nt) {
      const int d = dbase + 16 * nt + l16;
      #pragma unroll
      for (int mt = 0; mt < 2; ++mt)
        #pragma unroll
        for (int r = 0; r < 4; ++r) {
          const int tl = mt * 16 + quad * 4 + r;
          float hv = fast_tanh(a1[mt][nt][r] + b1v[nt]);
          uint_t pk = split_pack(hv);
          Hhi[tl][d] = (ushort_t)(pk >> 16);
          Hlo[tl][d] = (ushort_t)(pk & 0xffffu);
        }
    }
    __syncthreads();   // H(half) complete

    // ===== P4: W2 matmul over this half's 32 token-rows =====
    f32x4 acc2[2][2];
    #pragma unroll
    for (int mt = 0; mt < 2; ++mt)
      #pragma unroll
      for (int nt = 0; nt < 2; ++nt) acc2[mt][nt] = (f32x4)0.0f;

    #pragma unroll
    for (int k0 = 0; k0 < 8; ++k0) {
      const int dsl = k0 * 32 + quad * 8;
      short8 w2h[2], w2l[2];
      #pragma unroll
      for (int nt = 0; nt < 2; ++nt) {
        const int c = cbase + 16 * nt + l16;
        w2h[nt] = *(const short8*)(W2hi + c * DD + dsl);   // L1/L2-resident
        w2l[nt] = *(const short8*)(W2lo + c * DD + dsl);
      }
      #pragma unroll
      for (int mt = 0; mt < 2; ++mt) {
        const int tl = mt * 16 + l16;
        short8 ah = *(const short8*)(&Hhi[tl][dsl]);   // ds_read_b128
        short8 al = *(const short8*)(&Hlo[tl][dsl]);
        #pragma unroll
        for (int nt = 0; nt < 2; ++nt) {
          acc2[mt][nt] = __builtin_amdgcn_mfma_f32_16x16x32_bf16(ah, w2h[nt], acc2[mt][nt], 0, 0, 0);
          acc2[mt][nt] = __builtin_amdgcn_mfma_f32_16x16x32_bf16(ah, w2l[nt], acc2[mt][nt], 0, 0, 0);
          acc2[mt][nt] = __builtin_amdgcn_mfma_f32_16x16x32_bf16(al, w2h[nt], acc2[mt][nt], 0, 0, 0);
        }
      }
    }

    // ===== P5: tanh(+b2) + token-sum into registers =====
    // Addition order per pres: h0{mt0,mt1}, h1{mt0,mt1} == original mt0..3.
    {
      float s0 = 0.0f, s1 = 0.0f;
      #pragma unroll
      for (int mt = 0; mt < 2; ++mt)
        #pragma unroll
        for (int r = 0; r < 4; ++r) {
          s0 += fast_tanh(acc2[mt][0][r] + b2v[0]);
          s1 += fast_tanh(acc2[mt][1][r] + b2v[1]);
        }
      pres0 += s0;
      pres1 += s1;
    }
    __syncthreads();   // all waves done reading H(half) before next overwrite
  }

  // ---- epilogue: reduce + one atomic per (wave, nt) ----
  {
    float p = pres0;
    p += __shfl_xor(p, 16, 64);
    p += __shfl_xor(p, 32, 64);
    if (quad == 0) atomicAdd(&pool[b * DD + cbase + l16], p);
    float p1 = pres1;
    p1 += __shfl_xor(p1, 16, 64);
    p1 += __shfl_xor(p1, 32, 64);
    if (quad == 0) atomicAdd(&pool[b * DD + cbase + 16 + l16], p1);
  }
}

// ---------------------------------------------------------------------------
// Final: out[b,c] = (pool[b,:] / S) . Wc[c,:] + bc[c].  One block per b.
// ---------------------------------------------------------------------------
__global__ __launch_bounds__(64) void final_kernel(
    const float* __restrict__ pool, const float* __restrict__ Wc,
    const float* __restrict__ bc, float* __restrict__ out)
{
  const int b = blockIdx.x;
  const int t = threadIdx.x;
  float p0 = 0.0f, p1 = 0.0f;
  #pragma unroll
  for (int j = 0; j < 4; ++j) {
    float pv = pool[b * DD + t + 64 * j];
    p0 += pv * Wc[t + 64 * j];
    p1 += pv * Wc[DD + t + 64 * j];
  }
  #pragma unroll
  for (int off = 32; off; off >>= 1) {
    p0 += __shfl_xor(p0, off, 64);
    p1 += __shfl_xor(p1, off, 64);
  }
  if (t == 0) {
    out[b * CC + 0] = p0 * (1.0f / SS) + bc[0];
    out[b * CC + 1] = p1 * (1.0f / SS) + bc[1];
  }
}

extern "C" void kernel_launch(void* const* d_in, const int* in_sizes, int n_in,
                              void* d_out, int out_size, void* d_ws, size_t ws_size,
                              hipStream_t stream) {
  const int*   x   = (const int*)  d_in[0];
  const float* emb = (const float*)d_in[1];
  const float* W1  = (const float*)d_in[2];
  const float* b1  = (const float*)d_in[3];
  const float* W2  = (const float*)d_in[4];
  const float* b2  = (const float*)d_in[5];
  const float* Wc  = (const float*)d_in[6];
  const float* bc  = (const float*)d_in[7];
  float* out = (float*)d_out;
  char*  ws  = (char*)d_ws;

  prep_kernel<<<1090, 256, 0, stream>>>(emb, W1, W2, ws);
  main_kernel<<<BB * NW, 512, 0, stream>>>(
      x,
      (const uint_t*)  (ws + WS_GPK_B),
      (const ushort_t*)(ws + WS_ATHI_B), (const ushort_t*)(ws + WS_ATLO_B),
      b1,
      (const ushort_t*)(ws + WS_W2HI_B), (const ushort_t*)(ws + WS_W2LO_B),
      b2,
      (float*)(ws + WS_POOL_B));
  final_kernel<<<BB, 64, 0, stream>>>((const float*)(ws + WS_POOL_B), Wc, bc, out);
}

// Round 3
// 184.561 us; speedup vs baseline: 1.8860x; 1.5069x over previous
//
#include <hip/hip_runtime.h>
#include <hip/hip_bf16.h>
#include <math.h>

// Problem constants (match reference)
#define BB  32
#define SS  4096
#define VV  256
#define DD  256
#define CC  2
#define WIN 64
#define NW  64   // SS/WIN

typedef unsigned short ushort_t;
typedef unsigned int   uint_t;
typedef __attribute__((ext_vector_type(8))) short short8;    // 8 bf16 (4 VGPRs)
typedef __attribute__((ext_vector_type(4))) float f32x4;

// Workspace layout (byte offsets). Total 573440 B.
#define WS_ATHI_B 0u          // ushort Athi[64][64]   8192  (A-op layout: [t][s])
#define WS_ATLO_B 8192u       // ushort Atlo[64][64]   8192
#define WS_GPK_B  16384u      // uint   gpk[256][256]  262144 (hi<<16 | lo per elem)
#define WS_W2HI_B 278528u     // ushort W2hi[256][256] 131072
#define WS_W2LO_B 409600u     // ushort W2lo[256][256] 131072
#define WS_POOL_B 540672u     // float  pool[32][256]  32768

#define HP 264    // H plane row stride in shorts (256 + 8 pad)

__device__ __forceinline__ float fast_tanh(float v) {
  float e = __expf(2.0f * v);
  return 1.0f - __fdividef(2.0f, e + 1.0f);
}

// Truncation-based bf16 split: v ~= hi + lo with |err| <= 2^-17 * |v|.
__device__ __forceinline__ uint_t split_pack(float v) {
  uint_t b  = __float_as_uint(v);
  uint_t hi = b & 0xffff0000u;
  float  r  = v - __uint_as_float(hi);
  uint_t lo = __float_as_uint(r) >> 16;
  return hi | lo;
}

// Pack hi/lo halves of two packed u32 into bf16 pair dwords via v_perm.
__device__ __forceinline__ uint_t perm_hi(uint_t p0, uint_t p1) {
  return __builtin_amdgcn_perm(p1, p0, 0x07060302u);
}
__device__ __forceinline__ uint_t perm_lo(uint_t p0, uint_t p1) {
  return __builtin_amdgcn_perm(p1, p0, 0x05040100u);
}

union u4s8 { uint_t u[4]; short8 v; };

// ---------------------------------------------------------------------------
// Prep grid (1090 blocks): unchanged from the verified 123 us version.
// ---------------------------------------------------------------------------
__global__ __launch_bounds__(256) void prep_kernel(
    const float* __restrict__ emb, const float* __restrict__ W1,
    const float* __restrict__ W2, char* __restrict__ ws)
{
  const int blk = blockIdx.x;
  const int tid = threadIdx.x;
  ushort_t* Athi = (ushort_t*)(ws + WS_ATHI_B);
  ushort_t* Atlo = (ushort_t*)(ws + WS_ATLO_B);
  uint_t*   gpk  = (uint_t*)  (ws + WS_GPK_B);
  ushort_t* W2hi = (ushort_t*)(ws + WS_W2HI_B);
  ushort_t* W2lo = (ushort_t*)(ws + WS_W2LO_B);
  float*    pool = (float*)   (ws + WS_POOL_B);

  if (blk == 0) {
    if (tid < WIN) {
      const int s = tid;
      const float omega = 60.0f * 2.0f * 3.14159265358979323846f / 4095.0f;
      float row[WIN];
      float sum = 0.0f;
      for (int t = 0; t < WIN; ++t) {
        float e = expf(cosf(omega * (float)(s - t)));
        row[t] = e;
        sum += e;
      }
      const float inv = 1.0f / sum;
      for (int t = 0; t < WIN; ++t) {
        uint_t pk = split_pack(row[t] * inv);
        Athi[t * WIN + s] = (ushort_t)(pk >> 16);
        Atlo[t * WIN + s] = (ushort_t)(pk & 0xffffu);
      }
    }
  } else if (blk == 1) {
    for (int i = tid; i < BB * DD; i += 256) pool[i] = 0.0f;
  } else if (blk < 1026) {
    const int gv = blk - 2;            // 0..1023
    const int d0 = (gv & 15) * 16;     // 16 d-columns
    const int v0 = (gv >> 4) * 4;      // 4 v-rows
    __shared__ float er[4 * DD];       // 4 KB
    __shared__ float ps[4][16][17];    // padded partials
    *(float4*)(er + tid * 4) = *(const float4*)(emb + v0 * DD + tid * 4);
    __syncthreads();
    const int kq = tid & 15;           // k-strip: [16kq, 16kq+16)
    const int dl = tid >> 4;           // 0..15
    const int d  = d0 + dl;
    float4 wv[4];
    #pragma unroll
    for (int j = 0; j < 4; ++j)
      wv[j] = *(const float4*)(W1 + d * DD + 16 * kq + 4 * j);  // coalesced
    #pragma unroll
    for (int v = 0; v < 4; ++v) {
      float a = 0.0f;
      #pragma unroll
      for (int j = 0; j < 4; ++j) {
        float4 e = *(const float4*)(er + v * DD + 16 * kq + 4 * j);
        a += e.x * wv[j].x + e.y * wv[j].y + e.z * wv[j].z + e.w * wv[j].w;
      }
      ps[v][dl][kq] = a;
    }
    __syncthreads();
    if (tid < 64) {
      const int v = tid >> 4, dr = tid & 15;
      float s = 0.0f;
      #pragma unroll
      for (int k = 0; k < 16; ++k) s += ps[v][dr][k];
      gpk[(v0 + v) * DD + d0 + dr] = split_pack(s);
    }
  } else {
    const int c0 = (blk - 1026) * 4;
    #pragma unroll
    for (int i = 0; i < 4; ++i) {
      const int c = c0 + i;
      uint_t pk = split_pack(W2[c * DD + tid]);
      W2hi[c * DD + tid] = (ushort_t)(pk >> 16);
      W2lo[c * DD + tid] = (ushort_t)(pk & 0xffffu);
    }
  }
}

// ---------------------------------------------------------------------------
// Main fused kernel — round-0 shape (one block per (b,n), 512 thr, 2 blk/CU)
// with three register-neutral fixes:
//  (a) REAL write swizzle: column ds = d ^ ((tl & 8) << 1). The 4.19M
//      SQ_LDS_BANK_CONFLICT was the P3 b16 stores: bank = 16*quad + 8*nt +
//      l16/2 (+const) put quads {0,2},{1,3} on the same 8-bank groups. The
//      XOR (= flip column block on row-bit3 = quad-bit1) spreads the 4 quads
//      over all 32 banks. P4 un-swizzles with dsl ^ ((l16&8)<<1); read stays
//      at the exact 8-phase minimum (XOR only permutes quads within each
//      bank-collision group). 16B alignment preserved.
//  (b) mt-outer P2 with fused P3: tanh/split/store VALU for tile mt issues
//      between mt and mt+1's independent MFMA chains (dual-issue), acc1 live
//      drops 32->8 AGPRs, LDS-write burst spreads out. Per-accumulator MFMA
//      order is unchanged -> bit-identical numerics.
//  (c) s_setprio(1) around P4's per-k0 MFMA cluster (T5; the two resident
//      blocks sit in different phases -> role diversity to arbitrate).
// Round-1/2 lesson: stay inside the 128-reg (V+A) budget of (512,4); no
// state carried across windows, no extra buffering.
// ---------------------------------------------------------------------------
__global__ __launch_bounds__(512, 4) void main_kernel(
    const int*      __restrict__ x,    const uint_t* __restrict__ gpk,
    const ushort_t* __restrict__ Athi, const ushort_t* __restrict__ Atlo,
    const float*    __restrict__ b1,
    const ushort_t* __restrict__ W2hi, const ushort_t* __restrict__ W2lo,
    const float*    __restrict__ b2,   float* __restrict__ pool)
{
  __shared__ ushort_t Hhi[WIN][HP];   // 33792 B
  __shared__ ushort_t Hlo[WIN][HP];   // 33792 B (total 67584 -> 2 blocks/CU)

  const int tid  = threadIdx.x;
  const int lane = tid & 63;
  const int w    = tid >> 6;       // 0..7
  const int quad = lane >> 4;
  const int l16  = lane & 15;
  const int b = blockIdx.x >> 6;
  const int n = blockIdx.x & 63;

  const int dbase = 32 * w;        // this wave's d-slice (P2) == c-slice (P4)
  const int cbase = dbase;
  const int rsw   = (l16 & 8) << 1;   // P4 read un-swizzle (16 shorts)

  // --- P1: gather (packed u32), issued first so latency overlaps setup ---
  const int xv = x[b * SS + n * WIN + lane];
  uint_t q[2][2][8];
  #pragma unroll
  for (int k0 = 0; k0 < 2; ++k0) {
    const int sl = k0 * 32 + quad * 8;
    int xs[8];
    #pragma unroll
    for (int j = 0; j < 8; ++j) xs[j] = __shfl(xv, sl + j, 64);
    #pragma unroll
    for (int nt = 0; nt < 2; ++nt) {
      const int d = dbase + 16 * nt + l16;
      #pragma unroll
      for (int j = 0; j < 8; ++j) q[k0][nt][j] = gpk[xs[j] * DD + d];
    }
  }

  float b1v[2], b2v[2];
  #pragma unroll
  for (int nt = 0; nt < 2; ++nt) {
    b1v[nt] = b1[dbase + 16 * nt + l16];
    b2v[nt] = b2[cbase + 16 * nt + l16];
  }

  // Build all B-fragments upfront (q dies here).
  short8 bh[2][2], bl[2][2];
  #pragma unroll
  for (int k0 = 0; k0 < 2; ++k0)
    #pragma unroll
    for (int nt = 0; nt < 2; ++nt) {
      u4s8 h, l;
      #pragma unroll
      for (int p = 0; p < 4; ++p) {
        h.u[p] = perm_hi(q[k0][nt][2 * p], q[k0][nt][2 * p + 1]);
        l.u[p] = perm_lo(q[k0][nt][2 * p], q[k0][nt][2 * p + 1]);
      }
      bh[k0][nt] = h.v;
      bl[k0][nt] = l.v;
    }

  // --- P2+P3 fused, mt-outer: MFMA tile then its tanh/split/store ---
  #pragma unroll
  for (int mt = 0; mt < 4; ++mt) {
    f32x4 a1[2];
    a1[0] = (f32x4)0.0f;
    a1[1] = (f32x4)0.0f;
    #pragma unroll
    for (int k0 = 0; k0 < 2; ++k0) {
      const int sl = k0 * 32 + quad * 8;
      const int t  = mt * 16 + l16;
      short8 ah = *(const short8*)(Athi + t * WIN + sl);   // L1-resident
      short8 al = *(const short8*)(Atlo + t * WIN + sl);
      #pragma unroll
      for (int nt = 0; nt < 2; ++nt) {
        a1[nt] = __builtin_amdgcn_mfma_f32_16x16x32_bf16(ah, bh[k0][nt], a1[nt], 0, 0, 0);
        a1[nt] = __builtin_amdgcn_mfma_f32_16x16x32_bf16(ah, bl[k0][nt], a1[nt], 0, 0, 0);
        a1[nt] = __builtin_amdgcn_mfma_f32_16x16x32_bf16(al, bh[k0][nt], a1[nt], 0, 0, 0);
      }
    }
    // P3 for this mt: tanh(+b1), split, swizzled store.
    // Row tl = mt*16 + quad*4 + r  ->  tl&8 = (quad&2)<<2, swizzle const/quad.
    const int wsw = (quad & 2) << 3;    // 0 or 16 shorts
    #pragma unroll
    for (int nt = 0; nt < 2; ++nt) {
      const int ds = (dbase + 16 * nt + l16) ^ wsw;
      #pragma unroll
      for (int r = 0; r < 4; ++r) {
        const int tl = mt * 16 + quad * 4 + r;
        float hv = fast_tanh(a1[nt][r] + b1v[nt]);
        uint_t pk = split_pack(hv);
        Hhi[tl][ds] = (ushort_t)(pk >> 16);
        Hlo[tl][ds] = (ushort_t)(pk & 0xffffu);
      }
    }
  }
  __syncthreads();   // the only barrier

  // --- P4: matmul2 MFMA, W2 double-buffered, A-frags direct b128 ---
  f32x4 acc2[4][2];
  #pragma unroll
  for (int mt = 0; mt < 4; ++mt)
    #pragma unroll
    for (int nt = 0; nt < 2; ++nt) acc2[mt][nt] = (f32x4)0.0f;

  short8 wh[2][2], wl[2][2];
  {
    const int dsl0 = quad * 8;
    #pragma unroll
    for (int nt = 0; nt < 2; ++nt) {
      const int c = cbase + 16 * nt + l16;
      wh[0][nt] = *(const short8*)(W2hi + c * DD + dsl0);
      wl[0][nt] = *(const short8*)(W2lo + c * DD + dsl0);
    }
  }

  #pragma unroll 2
  for (int k0 = 0; k0 < 8; ++k0) {
    const int cur = k0 & 1, nxt = cur ^ 1;
    const int dsl = k0 * 32 + quad * 8;
    if (k0 < 7) {
      const int dsln = dsl + 32;
      #pragma unroll
      for (int nt = 0; nt < 2; ++nt) {
        const int c = cbase + 16 * nt + l16;
        wh[nxt][nt] = *(const short8*)(W2hi + c * DD + dsln);   // prefetch k0+1
        wl[nxt][nt] = *(const short8*)(W2lo + c * DD + dsln);
      }
    }
    const int dsw = dsl ^ rsw;          // un-swizzle for row t = mt*16 + l16
    __builtin_amdgcn_s_setprio(1);
    #pragma unroll
    for (int mt = 0; mt < 4; ++mt) {
      const int t = mt * 16 + l16;
      short8 ah = *(const short8*)(&Hhi[t][dsw]);   // ds_read_b128, 8-phase min
      short8 al = *(const short8*)(&Hlo[t][dsw]);
      #pragma unroll
      for (int nt = 0; nt < 2; ++nt) {
        acc2[mt][nt] = __builtin_amdgcn_mfma_f32_16x16x32_bf16(ah, wh[cur][nt], acc2[mt][nt], 0, 0, 0);
        acc2[mt][nt] = __builtin_amdgcn_mfma_f32_16x16x32_bf16(ah, wl[cur][nt], acc2[mt][nt], 0, 0, 0);
        acc2[mt][nt] = __builtin_amdgcn_mfma_f32_16x16x32_bf16(al, wh[cur][nt], acc2[mt][nt], 0, 0, 0);
      }
    }
    __builtin_amdgcn_s_setprio(0);
  }

  // --- P5: tanh(+b2) + token-sum, one atomic per (b,c) ---
  #pragma unroll
  for (int nt = 0; nt < 2; ++nt) {
    float p = 0.0f;
    #pragma unroll
    for (int mt = 0; mt < 4; ++mt)
      #pragma unroll
      for (int r = 0; r < 4; ++r)
        p += fast_tanh(acc2[mt][nt][r] + b2v[nt]);
    p += __shfl_xor(p, 16, 64);
    p += __shfl_xor(p, 32, 64);
    if (quad == 0) atomicAdd(&pool[b * DD + cbase + 16 * nt + l16], p);
  }
}

// ---------------------------------------------------------------------------
// Final: out[b,c] = (pool[b,:] / S) . Wc[c,:] + bc[c].  One block per b.
// ---------------------------------------------------------------------------
__global__ __launch_bounds__(64) void final_kernel(
    const float* __restrict__ pool, const float* __restrict__ Wc,
    const float* __restrict__ bc, float* __restrict__ out)
{
  const int b = blockIdx.x;
  const int t = threadIdx.x;
  float p0 = 0.0f, p1 = 0.0f;
  #pragma unroll
  for (int j = 0; j < 4; ++j) {
    float pv = pool[b * DD + t + 64 * j];
    p0 += pv * Wc[t + 64 * j];
    p1 += pv * Wc[DD + t + 64 * j];
  }
  #pragma unroll
  for (int off = 32; off; off >>= 1) {
    p0 += __shfl_xor(p0, off, 64);
    p1 += __shfl_xor(p1, off, 64);
  }
  if (t == 0) {
    out[b * CC + 0] = p0 * (1.0f / SS) + bc[0];
    out[b * CC + 1] = p1 * (1.0f / SS) + bc[1];
  }
}

extern "C" void kernel_launch(void* const* d_in, const int* in_sizes, int n_in,
                              void* d_out, int out_size, void* d_ws, size_t ws_size,
                              hipStream_t stream) {
  const int*   x   = (const int*)  d_in[0];
  const float* emb = (const float*)d_in[1];
  const float* W1  = (const float*)d_in[2];
  const float* b1  = (const float*)d_in[3];
  const float* W2  = (const float*)d_in[4];
  const float* b2  = (const float*)d_in[5];
  const float* Wc  = (const float*)d_in[6];
  const float* bc  = (const float*)d_in[7];
  float* out = (float*)d_out;
  char*  ws  = (char*)d_ws;

  prep_kernel<<<1090, 256, 0, stream>>>(emb, W1, W2, ws);
  main_kernel<<<BB * NW, 512, 0, stream>>>(
      x,
      (const uint_t*)  (ws + WS_GPK_B),
      (const ushort_t*)(ws + WS_ATHI_B), (const ushort_t*)(ws + WS_ATLO_B),
      b1,
      (const ushort_t*)(ws + WS_W2HI_B), (const ushort_t*)(ws + WS_W2LO_B),
      b2,
      (float*)(ws + WS_POOL_B));
  final_kernel<<<BB, 64, 0, stream>>>((const float*)(ws + WS_POOL_B), Wc, bc, out);
}